// Round 18
// baseline (223.167 us; speedup 1.0000x reference)
//
#include <hip/hip_runtime.h>

#define NN 100000
#define NE 3200000
#define BS 256                      // nodes per bucket
#define NBUCK 391                   // ceil(NN/BS); 391*256 = 100096
#define EPB 12500                   // edges per binA block: 256 blocks * 12500 = NE

typedef short bf16x8 __attribute__((ext_vector_type(8)));
typedef float f32x4  __attribute__((ext_vector_type(4)));

__device__ inline unsigned rne_bf16(float x) {
    unsigned u = __float_as_uint(x);
    return (u + 0x7fffu + ((u >> 16) & 1u)) >> 16;   // round-to-nearest-even
}
__device__ inline float bflo(unsigned u) { return __uint_as_float(u << 16); }
__device__ inline float bfhi(unsigned u) { return __uint_as_float(u & 0xffff0000u); }

// ===========================================================================
// L1: fused {gemm_n16 (W2@W3 -> M1), 16 blocks} + {hist_coarse, 256 blocks}
// ===========================================================================
__global__ __launch_bounds__(256) void l1_gemm_hist(const float* __restrict__ W2,
                                                    const float* __restrict__ W3,
                                                    float* __restrict__ M1,
                                                    const int* __restrict__ dst,
                                                    int* __restrict__ cntA) {
    __shared__ float As[16][260];
    __shared__ float Bs[256][16];
    __shared__ int hh[NBUCK];
    const int t = threadIdx.x;

    if (blockIdx.x < 16) {
        const int block_row = blockIdx.x * 16;
        for (int i = t; i < 1024; i += 256)
            ((float4*)&Bs[0][0])[i] = ((const float4*)W3)[i];
        for (int i = t; i < 1024; i += 256) {
            int idx = i << 2;
            int r = idx >> 8, c = idx & 255;
            int row = block_row + r;
            float4 v = ((const float4*)(W2 + (size_t)row * 256))[c >> 2];
            *(float4*)&As[r][c] = v;
        }
        __syncthreads();
        const int r = t >> 4, c = t & 15;
        float acc = 0.f;
#pragma unroll 8
        for (int k = 0; k < 256; ++k) acc += As[r][k] * Bs[k][c];
        M1[(size_t)(block_row + r) * 16 + c] = acc;
    } else {
        const int hb = blockIdx.x - 16;   // 0..255
        for (int i = t; i < NBUCK; i += 256) hh[i] = 0;
        __syncthreads();
        for (int e = hb * 256 + t; e < NE; e += 256 * 256)
            atomicAdd(&hh[dst[e] >> 8], 1);
        __syncthreads();
        for (int i = t; i < NBUCK; i += 256)
            if (hh[i]) atomicAdd(&cntA[i], hh[i]);
    }
}

// ===========================================================================
// L2: gemm_n16t: WcT[16][512] bf16 = (W1[512][256] @ M1[256][16])^T
// ===========================================================================
__global__ __launch_bounds__(256) void gemm_n16t(const float* __restrict__ A,
                                                 const float* __restrict__ B,
                                                 unsigned short* __restrict__ Wt) {
    __shared__ float As[16][260];
    __shared__ float Bs[256][16];
    const int t = threadIdx.x;
    const int block_row = blockIdx.x * 16;

    for (int i = t; i < 1024; i += 256)
        ((float4*)&Bs[0][0])[i] = ((const float4*)B)[i];
    for (int i = t; i < 1024; i += 256) {
        int idx = i << 2;
        int r = idx >> 8, c = idx & 255;
        int row = block_row + r;
        float4 v = ((const float4*)(A + (size_t)row * 256))[c >> 2];
        *(float4*)&As[r][c] = v;
    }
    __syncthreads();
    const int r = t >> 4, c = t & 15;
    float acc = 0.f;
#pragma unroll 8
    for (int k = 0; k < 256; ++k) acc += As[r][k] * Bs[k][c];
    Wt[(size_t)c * 512 + block_row + r] = (unsigned short)rne_bf16(acc);
}

// ===========================================================================
// binA: bucket the edges; packed = (src<<8)|(dst&255); EPB=12500 (256 blocks)
// ===========================================================================
__global__ __launch_bounds__(512) void binA(const int* __restrict__ src,
                                            const int* __restrict__ dst,
                                            const int* __restrict__ cntA,
                                            int* __restrict__ cursorCnt,
                                            unsigned* __restrict__ packed) {
    __shared__ int sscan[512];
    __shared__ int baseL[NBUCK];
    __shared__ int hist[NBUCK];
    const int t = threadIdx.x;
    const int lo = blockIdx.x * EPB, hi = lo + EPB;

    int v = (t < NBUCK) ? cntA[t] : 0;
    sscan[t] = v;
    __syncthreads();
    for (int off = 1; off < 512; off <<= 1) {
        int u = (t >= off) ? sscan[t - off] : 0;
        __syncthreads();
        sscan[t] += u;
        __syncthreads();
    }
    if (t < NBUCK) baseL[t] = sscan[t] - v;
    for (int i = t; i < NBUCK; i += 512) hist[i] = 0;
    __syncthreads();
    for (int i = lo + t; i < hi; i += 512)
        atomicAdd(&hist[dst[i] >> 8], 1);
    __syncthreads();
    for (int i = t; i < NBUCK; i += 512) {
        int c = hist[i];
        hist[i] = c ? baseL[i] + atomicAdd(&cursorCnt[i], c) : 0;
    }
    __syncthreads();
    for (int i = lo + t; i < hi; i += 512) {
        int d = dst[i];
        int pos = atomicAdd(&hist[d >> 8], 1);
        packed[pos] = ((unsigned)src[i] << 8) | (unsigned)(d & 255);
    }
}

// ===========================================================================
// gemm_xwc: Yb[NN][16] bf16 = bf16(X[NN][512]) @ WcT^T; LDS-staged MFMA
// ===========================================================================
__global__ __launch_bounds__(512) void gemm_xwc(const float* __restrict__ X,
                                                const unsigned short* __restrict__ WcT,
                                                unsigned short* __restrict__ Yb) {
    __shared__ unsigned short As[128][72];
    __shared__ unsigned short Ws[16][520];

    const int t = threadIdx.x;
    const int brow = blockIdx.x * 128;
    const int w = t >> 6, lane = t & 63;
    const int lrow = lane & 15, lk8 = (lane >> 4) * 8;

    for (int idx = t; idx < 1024; idx += 512) {
        int row = idx >> 6, ch = idx & 63;
        *(uint4*)&Ws[row][ch * 8] = ((const uint4*)(WcT + row * 512))[ch];
    }

    const int s_arow = t & 127, s_aq = t >> 7;
    const bool arow_ok = (brow + s_arow) < NN;
    const float* Ap0 = X + (size_t)(brow + s_arow) * 512 + s_aq * 16;

    f32x4 acc = {};

    for (int k0 = 0; k0 < 512; k0 += 64) {
        float4 f[4];
        if (arow_ok) {
            const float4* p = (const float4*)(Ap0 + k0);
#pragma unroll
            for (int i = 0; i < 4; ++i) f[i] = p[i];
        } else {
#pragma unroll
            for (int i = 0; i < 4; ++i) f[i] = make_float4(0.f, 0.f, 0.f, 0.f);
        }
        unsigned p8[8];
#pragma unroll
        for (int i = 0; i < 4; ++i) {
            p8[2 * i]     = rne_bf16(f[i].x) | (rne_bf16(f[i].y) << 16);
            p8[2 * i + 1] = rne_bf16(f[i].z) | (rne_bf16(f[i].w) << 16);
        }
        *(uint4*)&As[s_arow][s_aq * 16]     = make_uint4(p8[0], p8[1], p8[2], p8[3]);
        *(uint4*)&As[s_arow][s_aq * 16 + 8] = make_uint4(p8[4], p8[5], p8[6], p8[7]);
        __syncthreads();

#pragma unroll
        for (int ks = 0; ks < 2; ++ks) {
            bf16x8 af = *(const bf16x8*)&As[w * 16 + lrow][ks * 32 + lk8];
            bf16x8 bw = *(const bf16x8*)&Ws[lrow][k0 + ks * 32 + lk8];
            acc = __builtin_amdgcn_mfma_f32_16x16x32_bf16(af, bw, acc, 0, 0, 0);
        }
        __syncthreads();
    }

    const int col = lrow;
    const int rbase = brow + w * 16 + (lane >> 4) * 4;
#pragma unroll
    for (int r = 0; r < 4; ++r) {
        int row = rbase + r;
        if (row < NN)
            Yb[(size_t)row * 16 + col] = (unsigned short)rne_bf16(acc[r]);
    }
}

// ===========================================================================
// binB: per-bucket counting sort -> offs + srcs; 391 blocks, 256-node buckets
// ===========================================================================
__global__ __launch_bounds__(512) void binB(const unsigned* __restrict__ packed,
                                            const int* __restrict__ cntA,
                                            int* __restrict__ offs,
                                            int* __restrict__ srcs) {
    __shared__ int sscan[512];
    __shared__ int h[256];
    __shared__ int run[256];
    const int b = blockIdx.x, t = threadIdx.x;

    int v = (t < NBUCK) ? cntA[t] : 0;
    sscan[t] = v;
    __syncthreads();
    for (int off = 1; off < 512; off <<= 1) {
        int u = (t >= off) ? sscan[t - off] : 0;
        __syncthreads();
        sscan[t] += u;
        __syncthreads();
    }
    const int hi = sscan[b];
    const int lo = hi - cntA[b];

    if (t < 256) h[t] = 0;
    __syncthreads();
    for (int i = lo + t; i < hi; i += 512)
        atomicAdd(&h[packed[i] & 255], 1);
    __syncthreads();
    int mine = (t < 256) ? h[t] : 0;
    for (int off = 1; off < 256; off <<= 1) {
        int u = 0;
        if (t < 256 && t >= off) u = h[t - off];
        __syncthreads();
        if (t < 256) h[t] += u;
        __syncthreads();
    }
    if (t < 256) {
        int gbase = lo + (h[t] - mine);   // exclusive prefix within bucket
        int node = b * BS + t;
        if (node < NN) offs[node] = gbase;
        run[t] = gbase;
    }
    __syncthreads();
    for (int i = lo + t; i < hi; i += 512) {
        unsigned v2 = packed[i];
        int pos = atomicAdd(&run[v2 & 255], 1);
        srcs[pos] = (int)(v2 >> 8);
    }
    if (b == NBUCK - 1 && t == 0) offs[NN] = NE;
}

// ===========================================================================
// Aggregation: bf16 gather, fp32 accumulate; 8 threads/node, uint (2 feats),
// unroll-8 -> 800k threads (~3 waves/SIMD) for latency hiding
// ===========================================================================
template<bool OUT_F32>
__global__ __launch_bounds__(256) void agg16(const unsigned short* __restrict__ h,
                                             const int* __restrict__ offs,
                                             const int* __restrict__ srcs,
                                             void* __restrict__ outp) {
    int tid = blockIdx.x * 256 + threadIdx.x;
    int node = tid >> 3, f2 = tid & 7;
    if (node >= NN) return;
    int beg = offs[node], end = offs[node + 1];
    const unsigned short* hp = h + f2 * 2;
    float a0 = 0, a1 = 0;
    float b0 = 0, b1 = 0;
    float c0 = 0, c1 = 0;
    float d0 = 0, d1 = 0;
    int j = beg;
    for (; j + 8 <= end; j += 8) {
        int s0 = srcs[j],     s1 = srcs[j + 1], s2 = srcs[j + 2], s3 = srcs[j + 3];
        int s4 = srcs[j + 4], s5 = srcs[j + 5], s6 = srcs[j + 6], s7 = srcs[j + 7];
        unsigned u0 = *(const unsigned*)(hp + (size_t)s0 * 16);
        unsigned u1 = *(const unsigned*)(hp + (size_t)s1 * 16);
        unsigned u2 = *(const unsigned*)(hp + (size_t)s2 * 16);
        unsigned u3 = *(const unsigned*)(hp + (size_t)s3 * 16);
        unsigned u4 = *(const unsigned*)(hp + (size_t)s4 * 16);
        unsigned u5 = *(const unsigned*)(hp + (size_t)s5 * 16);
        unsigned u6 = *(const unsigned*)(hp + (size_t)s6 * 16);
        unsigned u7 = *(const unsigned*)(hp + (size_t)s7 * 16);
        a0 += bflo(u0); a1 += bfhi(u0);
        b0 += bflo(u1); b1 += bfhi(u1);
        c0 += bflo(u2); c1 += bfhi(u2);
        d0 += bflo(u3); d1 += bfhi(u3);
        a0 += bflo(u4); a1 += bfhi(u4);
        b0 += bflo(u5); b1 += bfhi(u5);
        c0 += bflo(u6); c1 += bfhi(u6);
        d0 += bflo(u7); d1 += bfhi(u7);
    }
    for (; j < end; ++j) {
        unsigned u = *(const unsigned*)(hp + (size_t)srcs[j] * 16);
        a0 += bflo(u); a1 += bfhi(u);
    }
    float r0 = (a0 + b0) + (c0 + d0);
    float r1 = (a1 + b1) + (c1 + d1);
    if (OUT_F32) {
        ((float2*)outp)[(size_t)node * 8 + f2] = make_float2(r0, r1);
    } else {
        ((unsigned*)outp)[(size_t)node * 8 + f2] = rne_bf16(r0) | (rne_bf16(r1) << 16);
    }
}

// ===========================================================================
extern "C" void kernel_launch(void* const* d_in, const int* in_sizes, int n_in,
                              void* d_out, int out_size, void* d_ws, size_t ws_size,
                              hipStream_t stream) {
    const float* X   = (const float*)d_in[0];   // [100000, 512]
    const int*   src = (const int*)d_in[1];     // [3200000]
    const int*   dst = (const int*)d_in[2];     // [3200000]
    const float* W1  = (const float*)d_in[3];   // [512, 256]
    const float* W2  = (const float*)d_in[4];   // [256, 256]
    const float* W3  = (const float*)d_in[5];   // [256, 16]
    float* out = (float*)d_out;                 // [100000, 16]

    char* ws = (char*)d_ws;
    unsigned short* Yb = (unsigned short*)ws;   ws += (size_t)NN * 16 * 2;   // 3.2 MB
    unsigned short* Gb = (unsigned short*)ws;   ws += (size_t)NN * 16 * 2;   // 3.2 MB
    float* M1 = (float*)ws;                     ws += 256 * 16 * 4;
    unsigned short* WcT = (unsigned short*)ws;  ws += 16 * 512 * 2;
    unsigned* packed = (unsigned*)ws;           ws += (size_t)NE * 4;        // 12.8 MB
    int* srcs       = (int*)ws;                 ws += (size_t)NE * 4;        // 12.8 MB
    int* offs       = (int*)ws;                 ws += ((size_t)NN + 4) * 4;  // 400 KB
    int* cntA       = (int*)ws;                 ws += 512 * 4;
    int* cursorCnt  = (int*)ws;                 ws += 512 * 4;

    // zero cntA + cursorCnt (contiguous, 512 ints each)
    hipMemsetAsync(cntA, 0, 1024 * 4, stream);

    // L1: W2@W3 -> M1  ||  coarse histogram of dst (391 buckets of 256 nodes)
    l1_gemm_hist<<<16 + 256, 256, 0, stream>>>(W2, W3, M1, dst, cntA);

    // L2: (W1@M1)^T -> WcT bf16
    gemm_n16t<<<32, 256, 0, stream>>>(W1, M1, WcT);

    // binA: bucket the edges (256 blocks, EPB=12500 — unchanged from R17)
    binA<<<256, 512, 0, stream>>>(src, dst, cntA, cursorCnt, packed);

    // Yb = bf16(X @ Wc)
    gemm_xwc<<<(NN + 127) / 128, 512, 0, stream>>>(X, WcT, Yb);

    // binB: per-bucket counting sort -> offs, srcs (391 blocks, 256-node buckets)
    binB<<<NBUCK, 512, 0, stream>>>(packed, cntA, offs, srcs);

    // out = A^3 Y : three width-16 aggregations (bf16, bf16, fp32-out)
    const int agg_blocks = (NN * 8 + 255) / 256;   // 3125
    agg16<false><<<agg_blocks, 256, 0, stream>>>(Yb, offs, srcs, Gb);
    agg16<false><<<agg_blocks, 256, 0, stream>>>(Gb, offs, srcs, Yb);
    agg16<true ><<<agg_blocks, 256, 0, stream>>>(Yb, offs, srcs, out);
}

// Round 19
// 204.675 us; speedup vs baseline: 1.0904x; 1.0904x over previous
//
#include <hip/hip_runtime.h>

#define NN 100000
#define NE 3200000
#define BS 512                      // nodes per bucket
#define NBUCK 196                   // ceil(NN/BS); 196*512 = 100352
#define EPB 12500                   // edges per binA block: 256 blocks * 12500 = NE
#define CAP 20000                   // padded bucket capacity (mean 16326, +28 sigma)

typedef short bf16x8 __attribute__((ext_vector_type(8)));
typedef float f32x4  __attribute__((ext_vector_type(4)));

__device__ inline unsigned rne_bf16(float x) {
    unsigned u = __float_as_uint(x);
    return (u + 0x7fffu + ((u >> 16) & 1u)) >> 16;   // round-to-nearest-even
}
__device__ inline float bflo(unsigned u) { return __uint_as_float(u << 16); }
__device__ inline float bfhi(unsigned u) { return __uint_as_float(u & 0xffff0000u); }

// ===========================================================================
// L1: gemm_n16: M1[256][16] = W2[256][256] @ W3[256][16]  (16 blocks)
// ===========================================================================
__global__ __launch_bounds__(256) void gemm_n16(const float* __restrict__ A,
                                                const float* __restrict__ B,
                                                float* __restrict__ C) {
    __shared__ float As[16][260];
    __shared__ float Bs[256][16];
    const int t = threadIdx.x;
    const int block_row = blockIdx.x * 16;

    for (int i = t; i < 1024; i += 256)
        ((float4*)&Bs[0][0])[i] = ((const float4*)B)[i];
    for (int i = t; i < 1024; i += 256) {
        int idx = i << 2;
        int r = idx >> 8, c = idx & 255;
        float4 v = ((const float4*)(A + (size_t)(block_row + r) * 256))[c >> 2];
        *(float4*)&As[r][c] = v;
    }
    __syncthreads();
    const int r = t >> 4, c = t & 15;
    float acc = 0.f;
#pragma unroll 8
    for (int k = 0; k < 256; ++k) acc += As[r][k] * Bs[k][c];
    C[(size_t)(block_row + r) * 16 + c] = acc;
}

// ===========================================================================
// L2: gemm_n16t: WcT[16][512] bf16 = (W1[512][256] @ M1[256][16])^T  (32 blocks)
// ===========================================================================
__global__ __launch_bounds__(256) void gemm_n16t(const float* __restrict__ A,
                                                 const float* __restrict__ B,
                                                 unsigned short* __restrict__ Wt) {
    __shared__ float As[16][260];
    __shared__ float Bs[256][16];
    const int t = threadIdx.x;
    const int block_row = blockIdx.x * 16;

    for (int i = t; i < 1024; i += 256)
        ((float4*)&Bs[0][0])[i] = ((const float4*)B)[i];
    for (int i = t; i < 1024; i += 256) {
        int idx = i << 2;
        int r = idx >> 8, c = idx & 255;
        float4 v = ((const float4*)(A + (size_t)(block_row + r) * 256))[c >> 2];
        *(float4*)&As[r][c] = v;
    }
    __syncthreads();
    const int r = t >> 4, c = t & 15;
    float acc = 0.f;
#pragma unroll 8
    for (int k = 0; k < 256; ++k) acc += As[r][k] * Bs[k][c];
    Wt[(size_t)c * 512 + block_row + r] = (unsigned short)rne_bf16(acc);
}

// ===========================================================================
// binA: bucket the edges into padded regions; packed = (src<<9)|(dst&511)
// bucket b's region = [b*CAP, b*CAP + cursor[b]); no count pass, no scan.
// ===========================================================================
__global__ __launch_bounds__(512) void binA(const int* __restrict__ src,
                                            const int* __restrict__ dst,
                                            int* __restrict__ cursor,
                                            unsigned* __restrict__ packed) {
    __shared__ int hist[NBUCK];
    const int t = threadIdx.x;
    const int lo = blockIdx.x * EPB, hi = lo + EPB;

    for (int i = t; i < NBUCK; i += 512) hist[i] = 0;
    __syncthreads();
    for (int i = lo + t; i < hi; i += 512)
        atomicAdd(&hist[dst[i] >> 9], 1);
    __syncthreads();
    for (int i = t; i < NBUCK; i += 512) {
        int c = hist[i];
        hist[i] = c ? i * CAP + atomicAdd(&cursor[i], c) : 0;
    }
    __syncthreads();
    for (int i = lo + t; i < hi; i += 512) {
        int d = dst[i];
        int pos = atomicAdd(&hist[d >> 9], 1);
        packed[pos] = ((unsigned)src[i] << 9) | (unsigned)(d & 511);
    }
}

// ===========================================================================
// gemm_xwc: Yb[NN][16] bf16 = bf16(X[NN][512]) @ WcT^T; LDS-staged MFMA
// ===========================================================================
__global__ __launch_bounds__(512) void gemm_xwc(const float* __restrict__ X,
                                                const unsigned short* __restrict__ WcT,
                                                unsigned short* __restrict__ Yb) {
    __shared__ unsigned short As[128][72];
    __shared__ unsigned short Ws[16][520];

    const int t = threadIdx.x;
    const int brow = blockIdx.x * 128;
    const int w = t >> 6, lane = t & 63;
    const int lrow = lane & 15, lk8 = (lane >> 4) * 8;

    for (int idx = t; idx < 1024; idx += 512) {
        int row = idx >> 6, ch = idx & 63;
        *(uint4*)&Ws[row][ch * 8] = ((const uint4*)(WcT + row * 512))[ch];
    }

    const int s_arow = t & 127, s_aq = t >> 7;
    const bool arow_ok = (brow + s_arow) < NN;
    const float* Ap0 = X + (size_t)(brow + s_arow) * 512 + s_aq * 16;

    f32x4 acc = {};

    for (int k0 = 0; k0 < 512; k0 += 64) {
        float4 f[4];
        if (arow_ok) {
            const float4* p = (const float4*)(Ap0 + k0);
#pragma unroll
            for (int i = 0; i < 4; ++i) f[i] = p[i];
        } else {
#pragma unroll
            for (int i = 0; i < 4; ++i) f[i] = make_float4(0.f, 0.f, 0.f, 0.f);
        }
        unsigned p8[8];
#pragma unroll
        for (int i = 0; i < 4; ++i) {
            p8[2 * i]     = rne_bf16(f[i].x) | (rne_bf16(f[i].y) << 16);
            p8[2 * i + 1] = rne_bf16(f[i].z) | (rne_bf16(f[i].w) << 16);
        }
        *(uint4*)&As[s_arow][s_aq * 16]     = make_uint4(p8[0], p8[1], p8[2], p8[3]);
        *(uint4*)&As[s_arow][s_aq * 16 + 8] = make_uint4(p8[4], p8[5], p8[6], p8[7]);
        __syncthreads();

#pragma unroll
        for (int ks = 0; ks < 2; ++ks) {
            bf16x8 af = *(const bf16x8*)&As[w * 16 + lrow][ks * 32 + lk8];
            bf16x8 bw = *(const bf16x8*)&Ws[lrow][k0 + ks * 32 + lk8];
            acc = __builtin_amdgcn_mfma_f32_16x16x32_bf16(af, bw, acc, 0, 0, 0);
        }
        __syncthreads();
    }

    const int col = lrow;
    const int rbase = brow + w * 16 + (lane >> 4) * 4;
#pragma unroll
    for (int r = 0; r < 4; ++r) {
        int row = rbase + r;
        if (row < NN)
            Yb[(size_t)row * 16 + col] = (unsigned short)rne_bf16(acc[r]);
    }
}

// ===========================================================================
// binB: per-bucket counting sort within padded region -> offsB/offsE + srcs
// ===========================================================================
__global__ __launch_bounds__(512) void binB(const unsigned* __restrict__ packed,
                                            const int* __restrict__ cursor,
                                            int* __restrict__ offsB,
                                            int* __restrict__ offsE,
                                            int* __restrict__ srcs) {
    __shared__ int h[512];
    __shared__ int run[512];
    const int b = blockIdx.x, t = threadIdx.x;
    const int lo = b * CAP;
    const int hi = lo + cursor[b];

    h[t] = 0;
    __syncthreads();
    for (int i = lo + t; i < hi; i += 512)
        atomicAdd(&h[packed[i] & 511], 1);
    __syncthreads();
    int mine = h[t];
    for (int off = 1; off < 512; off <<= 1) {
        int u = (t >= off) ? h[t - off] : 0;
        __syncthreads();
        h[t] += u;
        __syncthreads();
    }
    int gbase = lo + (h[t] - mine);   // exclusive prefix within bucket
    int node = b * BS + t;
    if (node < NN) { offsB[node] = gbase; offsE[node] = gbase + mine; }
    run[t] = gbase;
    __syncthreads();
    for (int i = lo + t; i < hi; i += 512) {
        unsigned v2 = packed[i];
        int pos = atomicAdd(&run[v2 & 511], 1);
        srcs[pos] = (int)(v2 >> 9);
    }
}

// ===========================================================================
// Aggregation: bf16 gather, fp32 accumulate; 8 threads/node, uint (2 feats),
// unroll-8; segments from offsB/offsE
// ===========================================================================
template<bool OUT_F32>
__global__ __launch_bounds__(256) void agg16(const unsigned short* __restrict__ h,
                                             const int* __restrict__ offsB,
                                             const int* __restrict__ offsE,
                                             const int* __restrict__ srcs,
                                             void* __restrict__ outp) {
    int tid = blockIdx.x * 256 + threadIdx.x;
    int node = tid >> 3, f2 = tid & 7;
    if (node >= NN) return;
    int beg = offsB[node], end = offsE[node];
    const unsigned short* hp = h + f2 * 2;
    float a0 = 0, a1 = 0;
    float b0 = 0, b1 = 0;
    float c0 = 0, c1 = 0;
    float d0 = 0, d1 = 0;
    int j = beg;
    for (; j + 8 <= end; j += 8) {
        int s0 = srcs[j],     s1 = srcs[j + 1], s2 = srcs[j + 2], s3 = srcs[j + 3];
        int s4 = srcs[j + 4], s5 = srcs[j + 5], s6 = srcs[j + 6], s7 = srcs[j + 7];
        unsigned u0 = *(const unsigned*)(hp + (size_t)s0 * 16);
        unsigned u1 = *(const unsigned*)(hp + (size_t)s1 * 16);
        unsigned u2 = *(const unsigned*)(hp + (size_t)s2 * 16);
        unsigned u3 = *(const unsigned*)(hp + (size_t)s3 * 16);
        unsigned u4 = *(const unsigned*)(hp + (size_t)s4 * 16);
        unsigned u5 = *(const unsigned*)(hp + (size_t)s5 * 16);
        unsigned u6 = *(const unsigned*)(hp + (size_t)s6 * 16);
        unsigned u7 = *(const unsigned*)(hp + (size_t)s7 * 16);
        a0 += bflo(u0); a1 += bfhi(u0);
        b0 += bflo(u1); b1 += bfhi(u1);
        c0 += bflo(u2); c1 += bfhi(u2);
        d0 += bflo(u3); d1 += bfhi(u3);
        a0 += bflo(u4); a1 += bfhi(u4);
        b0 += bflo(u5); b1 += bfhi(u5);
        c0 += bflo(u6); c1 += bfhi(u6);
        d0 += bflo(u7); d1 += bfhi(u7);
    }
    for (; j < end; ++j) {
        unsigned u = *(const unsigned*)(hp + (size_t)srcs[j] * 16);
        a0 += bflo(u); a1 += bfhi(u);
    }
    float r0 = (a0 + b0) + (c0 + d0);
    float r1 = (a1 + b1) + (c1 + d1);
    if (OUT_F32) {
        ((float2*)outp)[(size_t)node * 8 + f2] = make_float2(r0, r1);
    } else {
        ((unsigned*)outp)[(size_t)node * 8 + f2] = rne_bf16(r0) | (rne_bf16(r1) << 16);
    }
}

// ===========================================================================
extern "C" void kernel_launch(void* const* d_in, const int* in_sizes, int n_in,
                              void* d_out, int out_size, void* d_ws, size_t ws_size,
                              hipStream_t stream) {
    const float* X   = (const float*)d_in[0];   // [100000, 512]
    const int*   src = (const int*)d_in[1];     // [3200000]
    const int*   dst = (const int*)d_in[2];     // [3200000]
    const float* W1  = (const float*)d_in[3];   // [512, 256]
    const float* W2  = (const float*)d_in[4];   // [256, 256]
    const float* W3  = (const float*)d_in[5];   // [256, 16]
    float* out = (float*)d_out;                 // [100000, 16]

    char* ws = (char*)d_ws;
    unsigned short* Yb = (unsigned short*)ws;   ws += (size_t)NN * 16 * 2;   // 3.2 MB
    unsigned short* Gb = (unsigned short*)ws;   ws += (size_t)NN * 16 * 2;   // 3.2 MB
    float* M1 = (float*)ws;                     ws += 256 * 16 * 4;
    unsigned short* WcT = (unsigned short*)ws;  ws += 16 * 512 * 2;
    unsigned* packed = (unsigned*)ws;           ws += (size_t)NBUCK * CAP * 4;  // 15.7 MB
    int* srcs       = (int*)ws;                 ws += (size_t)NBUCK * CAP * 4;  // 15.7 MB
    int* offsB      = (int*)ws;                 ws += (size_t)NN * 4;           // 400 KB
    int* offsE      = (int*)ws;                 ws += (size_t)NN * 4;           // 400 KB
    int* cursor     = (int*)ws;                 ws += 256 * 4;

    // zero bucket cursors (1 KB)
    hipMemsetAsync(cursor, 0, 256 * 4, stream);

    // binA: bucket the edges into padded regions (no count pass needed)
    binA<<<256, 512, 0, stream>>>(src, dst, cursor, packed);

    // weight chain: M1 = W2@W3 ; WcT = (W1@M1)^T bf16
    gemm_n16<<<16, 256, 0, stream>>>(W2, W3, M1);
    gemm_n16t<<<32, 256, 0, stream>>>(W1, M1, WcT);

    // Yb = bf16(X @ Wc)
    gemm_xwc<<<(NN + 127) / 128, 512, 0, stream>>>(X, WcT, Yb);

    // binB: per-bucket counting sort -> offsB/offsE, srcs
    binB<<<NBUCK, 512, 0, stream>>>(packed, cursor, offsB, offsE, srcs);

    // out = A^3 Y : three width-16 aggregations (bf16, bf16, fp32-out)
    const int agg_blocks = (NN * 8 + 255) / 256;   // 3125
    agg16<false><<<agg_blocks, 256, 0, stream>>>(Yb, offsB, offsE, srcs, Gb);
    agg16<false><<<agg_blocks, 256, 0, stream>>>(Gb, offsB, offsE, srcs, Yb);
    agg16<true ><<<agg_blocks, 256, 0, stream>>>(Yb, offsB, offsE, srcs, out);
}

// Round 20
// 204.039 us; speedup vs baseline: 1.0937x; 1.0031x over previous
//
#include <hip/hip_runtime.h>

#define NN 100000
#define NE 3200000
#define BS 512                      // nodes per bucket
#define NBUCK 196                   // ceil(NN/BS); 196*512 = 100352
#define EPB 6250                    // edges per binA block: 512 blocks * 6250 = NE
#define CAP 20000                   // padded bucket capacity (mean 16326, +28 sigma)

typedef short bf16x8 __attribute__((ext_vector_type(8)));
typedef float f32x4  __attribute__((ext_vector_type(4)));

__device__ inline unsigned rne_bf16(float x) {
    unsigned u = __float_as_uint(x);
    return (u + 0x7fffu + ((u >> 16) & 1u)) >> 16;   // round-to-nearest-even
}
__device__ inline float bflo(unsigned u) { return __uint_as_float(u << 16); }
__device__ inline float bfhi(unsigned u) { return __uint_as_float(u & 0xffff0000u); }

// ===========================================================================
// L1: gemm_n16z: M1[256][16] = W2[256][256] @ W3[256][16]  (16 blocks)
//     + block 0 zeroes the bucket cursors (replaces the memset enqueue;
//       stream order guarantees visibility to binA)
// ===========================================================================
__global__ __launch_bounds__(256) void gemm_n16z(const float* __restrict__ A,
                                                 const float* __restrict__ B,
                                                 float* __restrict__ C,
                                                 int* __restrict__ cursor) {
    __shared__ float As[16][260];
    __shared__ float Bs[256][16];
    const int t = threadIdx.x;
    const int block_row = blockIdx.x * 16;

    if (blockIdx.x == 0) cursor[t] = 0;   // 256 >= NBUCK

    for (int i = t; i < 1024; i += 256)
        ((float4*)&Bs[0][0])[i] = ((const float4*)B)[i];
    for (int i = t; i < 1024; i += 256) {
        int idx = i << 2;
        int r = idx >> 8, c = idx & 255;
        float4 v = ((const float4*)(A + (size_t)(block_row + r) * 256))[c >> 2];
        *(float4*)&As[r][c] = v;
    }
    __syncthreads();
    const int r = t >> 4, c = t & 15;
    float acc = 0.f;
#pragma unroll 8
    for (int k = 0; k < 256; ++k) acc += As[r][k] * Bs[k][c];
    C[(size_t)(block_row + r) * 16 + c] = acc;
}

// ===========================================================================
// L2: gemm_n16t: WcT[16][512] bf16 = (W1[512][256] @ M1[256][16])^T  (32 blocks)
// ===========================================================================
__global__ __launch_bounds__(256) void gemm_n16t(const float* __restrict__ A,
                                                 const float* __restrict__ B,
                                                 unsigned short* __restrict__ Wt) {
    __shared__ float As[16][260];
    __shared__ float Bs[256][16];
    const int t = threadIdx.x;
    const int block_row = blockIdx.x * 16;

    for (int i = t; i < 1024; i += 256)
        ((float4*)&Bs[0][0])[i] = ((const float4*)B)[i];
    for (int i = t; i < 1024; i += 256) {
        int idx = i << 2;
        int r = idx >> 8, c = idx & 255;
        float4 v = ((const float4*)(A + (size_t)(block_row + r) * 256))[c >> 2];
        *(float4*)&As[r][c] = v;
    }
    __syncthreads();
    const int r = t >> 4, c = t & 15;
    float acc = 0.f;
#pragma unroll 8
    for (int k = 0; k < 256; ++k) acc += As[r][k] * Bs[k][c];
    Wt[(size_t)c * 512 + block_row + r] = (unsigned short)rne_bf16(acc);
}

// ===========================================================================
// binA: bucket the edges into padded regions; packed = (src<<9)|(dst&511)
// 512 blocks (2/CU); bucket b's region = [b*CAP, b*CAP + cursor[b])
// ===========================================================================
__global__ __launch_bounds__(512) void binA(const int* __restrict__ src,
                                            const int* __restrict__ dst,
                                            int* __restrict__ cursor,
                                            unsigned* __restrict__ packed) {
    __shared__ int hist[NBUCK];
    const int t = threadIdx.x;
    const int lo = blockIdx.x * EPB, hi = lo + EPB;

    for (int i = t; i < NBUCK; i += 512) hist[i] = 0;
    __syncthreads();
    for (int i = lo + t; i < hi; i += 512)
        atomicAdd(&hist[dst[i] >> 9], 1);
    __syncthreads();
    for (int i = t; i < NBUCK; i += 512) {
        int c = hist[i];
        hist[i] = c ? i * CAP + atomicAdd(&cursor[i], c) : 0;
    }
    __syncthreads();
    for (int i = lo + t; i < hi; i += 512) {
        int d = dst[i];
        int pos = atomicAdd(&hist[d >> 9], 1);
        packed[pos] = ((unsigned)src[i] << 9) | (unsigned)(d & 511);
    }
}

// ===========================================================================
// gemm_xwc: Yb[NN][16] bf16 = bf16(X[NN][512]) @ WcT^T; LDS-staged MFMA
// ===========================================================================
__global__ __launch_bounds__(512) void gemm_xwc(const float* __restrict__ X,
                                                const unsigned short* __restrict__ WcT,
                                                unsigned short* __restrict__ Yb) {
    __shared__ unsigned short As[128][72];
    __shared__ unsigned short Ws[16][520];

    const int t = threadIdx.x;
    const int brow = blockIdx.x * 128;
    const int w = t >> 6, lane = t & 63;
    const int lrow = lane & 15, lk8 = (lane >> 4) * 8;

    for (int idx = t; idx < 1024; idx += 512) {
        int row = idx >> 6, ch = idx & 63;
        *(uint4*)&Ws[row][ch * 8] = ((const uint4*)(WcT + row * 512))[ch];
    }

    const int s_arow = t & 127, s_aq = t >> 7;
    const bool arow_ok = (brow + s_arow) < NN;
    const float* Ap0 = X + (size_t)(brow + s_arow) * 512 + s_aq * 16;

    f32x4 acc = {};

    for (int k0 = 0; k0 < 512; k0 += 64) {
        float4 f[4];
        if (arow_ok) {
            const float4* p = (const float4*)(Ap0 + k0);
#pragma unroll
            for (int i = 0; i < 4; ++i) f[i] = p[i];
        } else {
#pragma unroll
            for (int i = 0; i < 4; ++i) f[i] = make_float4(0.f, 0.f, 0.f, 0.f);
        }
        unsigned p8[8];
#pragma unroll
        for (int i = 0; i < 4; ++i) {
            p8[2 * i]     = rne_bf16(f[i].x) | (rne_bf16(f[i].y) << 16);
            p8[2 * i + 1] = rne_bf16(f[i].z) | (rne_bf16(f[i].w) << 16);
        }
        *(uint4*)&As[s_arow][s_aq * 16]     = make_uint4(p8[0], p8[1], p8[2], p8[3]);
        *(uint4*)&As[s_arow][s_aq * 16 + 8] = make_uint4(p8[4], p8[5], p8[6], p8[7]);
        __syncthreads();

#pragma unroll
        for (int ks = 0; ks < 2; ++ks) {
            bf16x8 af = *(const bf16x8*)&As[w * 16 + lrow][ks * 32 + lk8];
            bf16x8 bw = *(const bf16x8*)&Ws[lrow][k0 + ks * 32 + lk8];
            acc = __builtin_amdgcn_mfma_f32_16x16x32_bf16(af, bw, acc, 0, 0, 0);
        }
        __syncthreads();
    }

    const int col = lrow;
    const int rbase = brow + w * 16 + (lane >> 4) * 4;
#pragma unroll
    for (int r = 0; r < 4; ++r) {
        int row = rbase + r;
        if (row < NN)
            Yb[(size_t)row * 16 + col] = (unsigned short)rne_bf16(acc[r]);
    }
}

// ===========================================================================
// binB: per-bucket counting sort within padded region -> offsB/offsE + srcs
// 196 blocks x 1024 threads (16 waves/CU)
// ===========================================================================
__global__ __launch_bounds__(1024) void binB(const unsigned* __restrict__ packed,
                                             const int* __restrict__ cursor,
                                             int* __restrict__ offsB,
                                             int* __restrict__ offsE,
                                             int* __restrict__ srcs) {
    __shared__ int h[512];
    __shared__ int run[512];
    const int b = blockIdx.x, t = threadIdx.x;
    const int lo = b * CAP;
    const int hi = lo + cursor[b];

    if (t < 512) h[t] = 0;
    __syncthreads();
    for (int i = lo + t; i < hi; i += 1024)
        atomicAdd(&h[packed[i] & 511], 1);
    __syncthreads();
    int mine = (t < 512) ? h[t] : 0;
    for (int off = 1; off < 512; off <<= 1) {
        int u = 0;
        if (t < 512 && t >= off) u = h[t - off];
        __syncthreads();
        if (t < 512) h[t] += u;
        __syncthreads();
    }
    if (t < 512) {
        int gbase = lo + (h[t] - mine);   // exclusive prefix within bucket
        int node = b * BS + t;
        if (node < NN) { offsB[node] = gbase; offsE[node] = gbase + mine; }
        run[t] = gbase;
    }
    __syncthreads();
    for (int i = lo + t; i < hi; i += 1024) {
        unsigned v2 = packed[i];
        int pos = atomicAdd(&run[v2 & 511], 1);
        srcs[pos] = (int)(v2 >> 9);
    }
}

// ===========================================================================
// Aggregation: bf16 gather, fp32 accumulate; 8 threads/node, uint (2 feats),
// unroll-8; segments from offsB/offsE
// ===========================================================================
template<bool OUT_F32>
__global__ __launch_bounds__(256) void agg16(const unsigned short* __restrict__ h,
                                             const int* __restrict__ offsB,
                                             const int* __restrict__ offsE,
                                             const int* __restrict__ srcs,
                                             void* __restrict__ outp) {
    int tid = blockIdx.x * 256 + threadIdx.x;
    int node = tid >> 3, f2 = tid & 7;
    if (node >= NN) return;
    int beg = offsB[node], end = offsE[node];
    const unsigned short* hp = h + f2 * 2;
    float a0 = 0, a1 = 0;
    float b0 = 0, b1 = 0;
    float c0 = 0, c1 = 0;
    float d0 = 0, d1 = 0;
    int j = beg;
    for (; j + 8 <= end; j += 8) {
        int s0 = srcs[j],     s1 = srcs[j + 1], s2 = srcs[j + 2], s3 = srcs[j + 3];
        int s4 = srcs[j + 4], s5 = srcs[j + 5], s6 = srcs[j + 6], s7 = srcs[j + 7];
        unsigned u0 = *(const unsigned*)(hp + (size_t)s0 * 16);
        unsigned u1 = *(const unsigned*)(hp + (size_t)s1 * 16);
        unsigned u2 = *(const unsigned*)(hp + (size_t)s2 * 16);
        unsigned u3 = *(const unsigned*)(hp + (size_t)s3 * 16);
        unsigned u4 = *(const unsigned*)(hp + (size_t)s4 * 16);
        unsigned u5 = *(const unsigned*)(hp + (size_t)s5 * 16);
        unsigned u6 = *(const unsigned*)(hp + (size_t)s6 * 16);
        unsigned u7 = *(const unsigned*)(hp + (size_t)s7 * 16);
        a0 += bflo(u0); a1 += bfhi(u0);
        b0 += bflo(u1); b1 += bfhi(u1);
        c0 += bflo(u2); c1 += bfhi(u2);
        d0 += bflo(u3); d1 += bfhi(u3);
        a0 += bflo(u4); a1 += bfhi(u4);
        b0 += bflo(u5); b1 += bfhi(u5);
        c0 += bflo(u6); c1 += bfhi(u6);
        d0 += bflo(u7); d1 += bfhi(u7);
    }
    for (; j < end; ++j) {
        unsigned u = *(const unsigned*)(hp + (size_t)srcs[j] * 16);
        a0 += bflo(u); a1 += bfhi(u);
    }
    float r0 = (a0 + b0) + (c0 + d0);
    float r1 = (a1 + b1) + (c1 + d1);
    if (OUT_F32) {
        ((float2*)outp)[(size_t)node * 8 + f2] = make_float2(r0, r1);
    } else {
        ((unsigned*)outp)[(size_t)node * 8 + f2] = rne_bf16(r0) | (rne_bf16(r1) << 16);
    }
}

// ===========================================================================
extern "C" void kernel_launch(void* const* d_in, const int* in_sizes, int n_in,
                              void* d_out, int out_size, void* d_ws, size_t ws_size,
                              hipStream_t stream) {
    const float* X   = (const float*)d_in[0];   // [100000, 512]
    const int*   src = (const int*)d_in[1];     // [3200000]
    const int*   dst = (const int*)d_in[2];     // [3200000]
    const float* W1  = (const float*)d_in[3];   // [512, 256]
    const float* W2  = (const float*)d_in[4];   // [256, 256]
    const float* W3  = (const float*)d_in[5];   // [256, 16]
    float* out = (float*)d_out;                 // [100000, 16]

    char* ws = (char*)d_ws;
    unsigned short* Yb = (unsigned short*)ws;   ws += (size_t)NN * 16 * 2;   // 3.2 MB
    unsigned short* Gb = (unsigned short*)ws;   ws += (size_t)NN * 16 * 2;   // 3.2 MB
    float* M1 = (float*)ws;                     ws += 256 * 16 * 4;
    unsigned short* WcT = (unsigned short*)ws;  ws += 16 * 512 * 2;
    unsigned* packed = (unsigned*)ws;           ws += (size_t)NBUCK * CAP * 4;  // 15.7 MB
    int* srcs       = (int*)ws;                 ws += (size_t)NBUCK * CAP * 4;  // 15.7 MB
    int* offsB      = (int*)ws;                 ws += (size_t)NN * 4;           // 400 KB
    int* offsE      = (int*)ws;                 ws += (size_t)NN * 4;           // 400 KB
    int* cursor     = (int*)ws;                 ws += 256 * 4;

    // weight chain step 1 (+ cursor zeroing for binA, via stream order)
    gemm_n16z<<<16, 256, 0, stream>>>(W2, W3, M1, cursor);

    // binA: bucket the edges into padded regions (512 blocks)
    binA<<<NE / EPB, 512, 0, stream>>>(src, dst, cursor, packed);

    // weight chain step 2: WcT = (W1@M1)^T bf16
    gemm_n16t<<<32, 256, 0, stream>>>(W1, M1, WcT);

    // Yb = bf16(X @ Wc)
    gemm_xwc<<<(NN + 127) / 128, 512, 0, stream>>>(X, WcT, Yb);

    // binB: per-bucket counting sort -> offsB/offsE, srcs (1024 threads)
    binB<<<NBUCK, 1024, 0, stream>>>(packed, cursor, offsB, offsE, srcs);

    // out = A^3 Y : three width-16 aggregations (bf16, bf16, fp32-out)
    const int agg_blocks = (NN * 8 + 255) / 256;   // 3125
    agg16<false><<<agg_blocks, 256, 0, stream>>>(Yb, offsB, offsE, srcs, Gb);
    agg16<false><<<agg_blocks, 256, 0, stream>>>(Gb, offsB, offsE, srcs, Yb);
    agg16<true ><<<agg_blocks, 256, 0, stream>>>(Yb, offsB, offsE, srcs, out);
}